// Round 1
// baseline (607.356 us; speedup 1.0000x reference)
//
#include <hip/hip_runtime.h>
#include <hip/hip_bf16.h>

// GPT-2 transformer block, MI355X bf16-MFMA. Round 8:
//  - split-K=2 for the two narrow-N GEMMs (attn-proj N=1024 K=1024, ff2
//    N=1024 K=4096): their 128^2 grid was 512 blocks = 2 blocks/CU, capping
//    occupancy at 21% and MfmaUtil at 25% (barrier-drain not hidden).
//    blockIdx.z = K-chunk -> 1024 co-resident blocks = 4 blocks/CU. Chunk 1
//    writes a raw fp32 partial (no bias) to a scratch buffer reusing dead
//    workspace; ln_kernel gains a third addend (fused reduction, ~free).
//  - attention: paired q-tiles (uniform block work), unchanged from R7.
//  - GEMMs: m97 recipe (global_load_lds w=16, 128^2 tile, BK=32), now with
//    separate K-length vs row-stride to support K-chunks.

typedef __attribute__((ext_vector_type(8))) short bf16x8;  // MFMA A/B frag
typedef __attribute__((ext_vector_type(4))) float f32x4;   // MFMA C/D frag

__device__ __forceinline__ float b2f(unsigned short u) {
  return __uint_as_float(((unsigned int)u) << 16);
}
__device__ __forceinline__ unsigned short f2b(float f) {  // RNE
  unsigned int u = __float_as_uint(f);
  u += 0x7fffu + ((u >> 16) & 1u);
  return (unsigned short)(u >> 16);
}
__device__ __forceinline__ unsigned int pk2b(float a, float b) {  // packed bf16x2
  __hip_bfloat162 h = __float22bfloat162_rn(make_float2(a, b));
  return *(unsigned int*)&h;
}
__device__ __forceinline__ void gload_lds16(const unsigned short* g, unsigned short* l) {
  __builtin_amdgcn_global_load_lds((const __attribute__((address_space(1))) void*)g,
                                   (__attribute__((address_space(3))) void*)l, 16, 0, 0);
}

// ---------------- fp32 -> bf16 elementwise ----------------
__global__ __launch_bounds__(256) void cvt_bf16(const float* __restrict__ in,
                                                unsigned short* __restrict__ out, long n) {
  long i = ((long)blockIdx.x * 256 + threadIdx.x) * 4;
  if (i >= n) return;
  float4 v = *(const float4*)(in + i);
  *(ushort4*)(out + i) = make_ushort4(f2b(v.x), f2b(v.y), f2b(v.z), f2b(v.w));
}

// ---------------- transpose fp32 [R,C] -> bf16 [C,R] ----------------
__global__ __launch_bounds__(256) void transpose_bf16(const float* __restrict__ in,
                                                      unsigned short* __restrict__ out,
                                                      int R, int C) {
  __shared__ float tile[32][33];
  int c0 = blockIdx.x * 32, r0 = blockIdx.y * 32;
  for (int i = threadIdx.y; i < 32; i += 8)
    tile[i][threadIdx.x] = in[(long)(r0 + i) * C + c0 + threadIdx.x];
  __syncthreads();
  for (int i = threadIdx.y; i < 32; i += 8)
    out[(long)(c0 + i) * R + r0 + threadIdx.x] = f2b(tile[threadIdx.x][i]);
}

// ---------------- bf16 MFMA GEMM (m97 recipe, optional split-K) ----------
// K = chunk length, Kstride = full row stride. blockIdx.z = K-chunk index:
// chunk 0 -> Cout (+bias), chunk 1 -> Cout2 (no bias). gridDim.z==1 for the
// non-split GEMMs (K == Kstride).
// EPI: 0=f32 out, 1=bf16 out, 2=bf16+relu,
//      3=qkv split: gn<2048 -> qk[m][2048] (q cols scaled by 0.125*log2e),
//                   gn>=2048 -> vt[b,h,s,t] packed ushort4 scatter.
template <int EPI>
__global__ __launch_bounds__(256) void gemm_bf16(const unsigned short* __restrict__ A,
                                                 const unsigned short* __restrict__ Bt,
                                                 const float* __restrict__ bias,
                                                 void* __restrict__ Cout,
                                                 void* __restrict__ Cout2,
                                                 int M, int N, int K, int Kstride) {
  __shared__ unsigned short As[128 * 32];
  __shared__ unsigned short Bs[128 * 32];
  int t = threadIdx.x;
  int bm = blockIdx.x * 128, bn = blockIdx.y * 128;
  int chunk = blockIdx.z;
  int w = t >> 6, lane = t & 63;
  int wr = w >> 1, wc = w & 1, quad = lane >> 4, l16 = lane & 15;
  int srow = t >> 2, scol = (t & 3) * 8;

  const unsigned short* Ap = A + (long)(bm + srow) * Kstride + (long)chunk * K + scol;
  const unsigned short* Bp = Bt + (long)(bn + srow) * Kstride + (long)chunk * K + scol;
  unsigned short* Asw = As + w * 512;
  unsigned short* Bsw = Bs + w * 512;

  f32x4 acc[4][4] = {};

  for (int k0 = 0; k0 < K; k0 += 32) {
    __syncthreads();
    gload_lds16(Ap + k0, Asw);
    gload_lds16(Ap + (long)64 * Kstride + k0, Asw + 2048);
    gload_lds16(Bp + k0, Bsw);
    gload_lds16(Bp + (long)64 * Kstride + k0, Bsw + 2048);
    __syncthreads();
    bf16x8 af[4], bfr[4];
#pragma unroll
    for (int i = 0; i < 4; ++i)
      af[i] = *(const bf16x8*)(As + (wr * 64 + i * 16 + l16) * 32 + quad * 8);
#pragma unroll
    for (int j = 0; j < 4; ++j)
      bfr[j] = *(const bf16x8*)(Bs + (wc * 64 + j * 16 + l16) * 32 + quad * 8);
#pragma unroll
    for (int i = 0; i < 4; ++i)
#pragma unroll
      for (int j = 0; j < 4; ++j)
        acc[i][j] = __builtin_amdgcn_mfma_f32_16x16x32_bf16(af[i], bfr[j], acc[i][j], 0, 0, 0);
  }

  void* Cbase = chunk ? Cout2 : Cout;
#pragma unroll
  for (int i = 0; i < 4; ++i) {
#pragma unroll
    for (int j = 0; j < 4; ++j) {
      int gn = bn + wc * 64 + j * 16 + l16;
      float bv = chunk ? 0.f : bias[gn];
      if (EPI == 3 && gn >= 2048) {
        int h = (gn >> 6) & 15, s = gn & 63;
        int gm0 = bm + wr * 64 + i * 16 + quad * 4;
        int b = gm0 >> 11, tt0 = gm0 & 2047;
        unsigned short* vt = (unsigned short*)Cout + 16777216L;
        ushort4 us;
        us.x = f2b(acc[i][j][0] + bv);
        us.y = f2b(acc[i][j][1] + bv);
        us.z = f2b(acc[i][j][2] + bv);
        us.w = f2b(acc[i][j][3] + bv);
        *(ushort4*)(vt + (((long)(b * 16 + h)) * 64 + s) * 2048 + tt0) = us;
      } else {
#pragma unroll
        for (int r = 0; r < 4; ++r) {
          int gm = bm + wr * 64 + i * 16 + quad * 4 + r;
          float v = acc[i][j][r] + bv;
          if (EPI == 2) v = fmaxf(v, 0.f);
          if (EPI == 0) {
            ((float*)Cbase)[(long)gm * N + gn] = v;
          } else if (EPI == 1 || EPI == 2) {
            ((unsigned short*)Cbase)[(long)gm * N + gn] = f2b(v);
          } else {  // EPI==3, q/k rows
            float sc = (gn < 1024) ? 0.18033688011112042f : 1.0f;  // 0.125*log2(e)
            ((unsigned short*)Cbase)[(long)gm * 2048 + gn] = f2b(v * sc);
          }
        }
      }
    }
  }
}

// ---------------- MFMA flash attention (paired q-tiles, uniform work) --------
// qk[m][2048] (q cols 0..1023 pre-scaled by 0.125*log2e, k cols 1024..2047),
// vt[b,h,s,t] at elem offset 16M. Grid (16, H, B), 256 thr = 4 waves; block i
// handles q-tiles qa=i and qb=31-i (33 tile-works each, uniform). Wave w owns
// q rows [qt*64+w*16, +16). P = exp2(S); l via ones-B MFMA.
__global__ __launch_bounds__(256) void attn_mfma(const unsigned short* __restrict__ qkv,
                                                 unsigned short* __restrict__ outp) {
  const int LD = 72;  // 144 B row stride; b64/b128 accesses land 2-way (free)
  __shared__ __align__(16) unsigned short Ks[64 * LD];
  __shared__ __align__(16) unsigned short Vts[64 * LD];
  __shared__ __align__(16) unsigned short Ps[4][16 * LD];  // wave-private P rows
  int qa = blockIdx.x, qb = 31 - qa;  // paired q-tiles
  int h = blockIdx.y, b = blockIdx.z;
  int t = threadIdx.x;
  int w = t >> 6, lane = t & 63, quad = lane >> 4, l16 = lane & 15;
  const unsigned short* qg = qkv + (long)(b * 2048) * 2048 + h * 64;
  const unsigned short* kg = qg + 1024;
  const unsigned short* vg = qkv + 16777216L + (((long)(b * 16 + h)) * 64) * 2048;
  unsigned short* Pw = &Ps[w][0];

  // Q frags for both q-tiles (B-operand for S^T): [n=l16 -> q][k=quad*8+j -> s]
  bf16x8 qfa[2], qfb[2];
#pragma unroll
  for (int ks = 0; ks < 2; ++ks) {
    qfa[ks] = *(const bf16x8*)(qg + (long)(qa * 64 + w * 16 + l16) * 2048 + ks * 32 + quad * 8);
    qfb[ks] = *(const bf16x8*)(qg + (long)(qb * 64 + w * 16 + l16) * 2048 + ks * 32 + quad * 8);
  }

  int sr = t >> 2, sc = (t & 3) * 16;
  const unsigned short* kp = kg + (long)sr * 2048 + sc;
  const unsigned short* vp = vg + (long)sr * 2048 + sc;
  int4 kv0 = *(const int4*)kp, kv1 = *(const int4*)(kp + 8);
  int4 vv0 = *(const int4*)vp, vv1 = *(const int4*)(vp + 8);
  kp += (long)64 * 2048;
  vp += 64;

  f32x4 oa[4] = {}, ob[4] = {};
  f32x4 la = {}, lb = {};
  const short ONE = 0x3F80;
  bf16x8 ones = {ONE, ONE, ONE, ONE, ONE, ONE, ONE, ONE};

  // per-tile work for one q-tile: S^T subtiles -> exp2 -> P (LDS) -> PV + l
  auto process = [&](const bf16x8* qf, int qt, int kt, f32x4* oacc, f32x4& lacc) {
    bool diag = (kt == qt);
#pragma unroll
    for (int rg = 0; rg < 4; ++rg) {
      bf16x8 kf0 = *(const bf16x8*)(Ks + (rg * 16 + l16) * LD + quad * 8);
      bf16x8 kf1 = *(const bf16x8*)(Ks + (rg * 16 + l16) * LD + 32 + quad * 8);
      f32x4 st = {};
      st = __builtin_amdgcn_mfma_f32_16x16x32_bf16(kf0, qf[0], st, 0, 0, 0);
      st = __builtin_amdgcn_mfma_f32_16x16x32_bf16(kf1, qf[1], st, 0, 0, 0);
      if (diag) {
        int kq = rg * 16 + quad * 4;  // k row within tile
        int qq = w * 16 + l16;        // q row within tile
#pragma unroll
        for (int r = 0; r < 4; ++r)
          if (kq + r > qq) st[r] = -1e30f;
      }
      unsigned int lo = pk2b(exp2f(st[0]), exp2f(st[1]));
      unsigned int hi = pk2b(exp2f(st[2]), exp2f(st[3]));
      *(uint2*)(Pw + l16 * LD + rg * 16 + quad * 4) = make_uint2(lo, hi);
    }
#pragma unroll
    for (int kc = 0; kc < 2; ++kc) {
      bf16x8 ap = *(const bf16x8*)(Pw + l16 * LD + kc * 32 + quad * 8);
      lacc = __builtin_amdgcn_mfma_f32_16x16x32_bf16(ap, ones, lacc, 0, 0, 0);
#pragma unroll
      for (int sg = 0; sg < 4; ++sg) {
        bf16x8 vf = *(const bf16x8*)(Vts + (sg * 16 + l16) * LD + kc * 32 + quad * 8);
        oacc[sg] = __builtin_amdgcn_mfma_f32_16x16x32_bf16(ap, vf, oacc[sg], 0, 0, 0);
      }
    }
  };

  for (int kt = 0; kt <= qb; ++kt) {
    __syncthreads();
    *(int4*)(Ks + sr * LD + sc) = kv0;
    *(int4*)(Ks + sr * LD + sc + 8) = kv1;
    *(int4*)(Vts + sr * LD + sc) = vv0;
    *(int4*)(Vts + sr * LD + sc + 8) = vv1;
    __syncthreads();
    if (kt < qb) {  // prefetch next tile behind compute
      kv0 = *(const int4*)kp; kv1 = *(const int4*)(kp + 8);
      vv0 = *(const int4*)vp; vv1 = *(const int4*)(vp + 8);
      kp += (long)64 * 2048;
      vp += 64;
    }
    process(qfb, qb, kt, ob, lb);          // heavy tile: every kt
    if (kt <= qa) process(qfa, qa, kt, oa, la);  // light tile: double-duty stage
  }

  auto epi = [&](int qt, f32x4* oacc, f32x4& lacc) {
#pragma unroll
    for (int r = 0; r < 4; ++r) {
      float invl = 1.f / lacc[r];
      int row = qt * 64 + w * 16 + quad * 4 + r;
      unsigned short* op = outp + ((long)(b * 2048 + row)) * 1024 + h * 64;
#pragma unroll
      for (int sg = 0; sg < 4; ++sg) op[sg * 16 + l16] = f2b(oacc[sg][r] * invl);
    }
  };
  epi(qa, oa, la);
  epi(qb, ob, lb);
}

// ---------------- residual + LayerNorm (optional 3rd addend: split-K partial) --
__global__ __launch_bounds__(256) void ln_kernel(const float* __restrict__ a,
                                                 const float* __restrict__ a2,
                                                 const float* __restrict__ res,
                                                 const float* __restrict__ gam,
                                                 const float* __restrict__ bet,
                                                 float* __restrict__ outf,
                                                 unsigned short* __restrict__ outb) {
  int row = blockIdx.x, t = threadIdx.x;
  float4 av = *(const float4*)(a + (long)row * 1024 + t * 4);
  float4 rv = *(const float4*)(res + (long)row * 1024 + t * 4);
  float v0 = av.x + rv.x, v1 = av.y + rv.y, v2 = av.z + rv.z, v3 = av.w + rv.w;
  if (a2) {
    float4 a2v = *(const float4*)(a2 + (long)row * 1024 + t * 4);
    v0 += a2v.x; v1 += a2v.y; v2 += a2v.z; v3 += a2v.w;
  }
  float s = v0 + v1 + v2 + v3;
  float ss = v0 * v0 + v1 * v1 + v2 * v2 + v3 * v3;
#pragma unroll
  for (int off = 32; off >= 1; off >>= 1) {
    s += __shfl_down(s, off);
    ss += __shfl_down(ss, off);
  }
  __shared__ float sb[4], ssb[4];
  __shared__ float mean_s, inv_s;
  int w = t >> 6, lane = t & 63;
  if (lane == 0) { sb[w] = s; ssb[w] = ss; }
  __syncthreads();
  if (t == 0) {
    float S = sb[0] + sb[1] + sb[2] + sb[3];
    float SS = ssb[0] + ssb[1] + ssb[2] + ssb[3];
    float mean = S * (1.f / 1024.f);
    float var = SS * (1.f / 1024.f) - mean * mean;
    mean_s = mean;
    inv_s = rsqrtf(var + 1e-5f);
  }
  __syncthreads();
  float mean = mean_s, inv = inv_s;
  int c = t * 4;
  float4 gv = *(const float4*)(gam + c);
  float4 bv = *(const float4*)(bet + c);
  float y0 = (v0 - mean) * inv * gv.x + bv.x;
  float y1 = (v1 - mean) * inv * gv.y + bv.y;
  float y2 = (v2 - mean) * inv * gv.z + bv.z;
  float y3 = (v3 - mean) * inv * gv.w + bv.w;
  *(float4*)(outf + (long)row * 1024 + c) = make_float4(y0, y1, y2, y3);
  if (outb) {
    *(ushort4*)(outb + (long)row * 1024 + c) = make_ushort4(f2b(y0), f2b(y1), f2b(y2), f2b(y3));
  }
}

extern "C" void kernel_launch(void* const* d_in, const int* in_sizes, int n_in,
                              void* d_out, int out_size, void* d_ws, size_t ws_size,
                              hipStream_t stream) {
  const float* x      = (const float*)d_in[0];
  const float* w_attn = (const float*)d_in[1];
  const float* b_attn = (const float*)d_in[2];
  const float* w_proj = (const float*)d_in[3];
  const float* b_proj = (const float*)d_in[4];
  const float* ln1_g  = (const float*)d_in[5];
  const float* ln1_b  = (const float*)d_in[6];
  const float* w_ff1  = (const float*)d_in[7];
  const float* b_ff1  = (const float*)d_in[8];
  const float* w_ff2  = (const float*)d_in[9];
  const float* b_ff2  = (const float*)d_in[10];
  const float* ln2_g  = (const float*)d_in[11];
  const float* ln2_b  = (const float*)d_in[12];

  const long M = 8192, E = 1024;
  char* ws = (char*)d_ws;
  unsigned short* xb   = (unsigned short*)ws; ws += M * E * 2;           // 16 MiB
  unsigned short* wTa  = (unsigned short*)ws; ws += 3072L * 1024 * 2;    // 6
  unsigned short* wTp  = (unsigned short*)ws; ws += 1024L * 1024 * 2;    // 2
  unsigned short* wTf1 = (unsigned short*)ws; ws += 4096L * 1024 * 2;    // 8
  unsigned short* wTf2 = (unsigned short*)ws; ws += 4096L * 1024 * 2;    // 8
  unsigned short* qkvb = (unsigned short*)ws; ws += M * 3072 * 2;        // 48 (qk rows 32 MiB | vt 16 MiB)
  unsigned short* attb = (unsigned short*)ws; ws += M * E * 2;           // 16
  float* a1f = (float*)ws; ws += M * E * 4;                              // 32
  float* x1f = (float*)ws; ws += M * E * 4;                              // 32
  unsigned short* x1b = (unsigned short*)ws; ws += M * E * 2;            // 16  => 184 MiB
  unsigned short* hb = qkvb;   // overlays consumed qkv+attb space
  float* f2 = a1f;
  // split-K partial buffers (reuse dead workspace, both 32 MiB fp32):
  //  - proj chunk-1: qk rows of qkvb are dead once attn_mfma finished; ln1
  //    consumes the partial BEFORE ff1 overwrites hb(=qkvb).
  float* prj1 = (float*)qkvb;
  //  - ff2 chunk-1: xb+wTa+wTp+wTf1 region (first 32 MiB of ws) is dead by ff2.
  float* ff21 = (float*)d_ws;

  cvt_bf16<<<dim3((M * E) / 4 / 256), dim3(256), 0, stream>>>(x, xb, M * E);
  transpose_bf16<<<dim3(3072 / 32, 1024 / 32), dim3(32, 8), 0, stream>>>(w_attn, wTa, 1024, 3072);
  transpose_bf16<<<dim3(1024 / 32, 1024 / 32), dim3(32, 8), 0, stream>>>(w_proj, wTp, 1024, 1024);
  transpose_bf16<<<dim3(4096 / 32, 1024 / 32), dim3(32, 8), 0, stream>>>(w_ff1, wTf1, 1024, 4096);
  transpose_bf16<<<dim3(1024 / 32, 4096 / 32), dim3(32, 8), 0, stream>>>(w_ff2, wTf2, 4096, 1024);
  // qkv projection, attention-layout epilogue
  gemm_bf16<3><<<dim3(64, 24, 1), dim3(256), 0, stream>>>(xb, wTa, b_attn, qkvb, nullptr, 8192, 3072, 1024, 1024);
  // MFMA flash attention (paired q-tiles, uniform work)
  attn_mfma<<<dim3(16, 16, 4), dim3(256), 0, stream>>>(qkvb, attb);
  // attn output projection: split-K=2 (1024 blocks, 4/CU)
  gemm_bf16<0><<<dim3(64, 8, 2), dim3(256), 0, stream>>>(attb, wTp, b_proj, a1f, prj1, 8192, 1024, 512, 1024);
  ln_kernel<<<dim3(8192), dim3(256), 0, stream>>>(a1f, prj1, x, ln1_g, ln1_b, x1f, x1b);
  gemm_bf16<2><<<dim3(64, 32, 1), dim3(256), 0, stream>>>(x1b, wTf1, b_ff1, hb, nullptr, 8192, 4096, 1024, 1024);
  // ff2: split-K=2 (1024 blocks, 4/CU), K chunks of 2048
  gemm_bf16<0><<<dim3(64, 8, 2), dim3(256), 0, stream>>>(hb, wTf2, b_ff2, f2, ff21, 8192, 1024, 2048, 4096);
  ln_kernel<<<dim3(8192), dim3(256), 0, stream>>>(f2, ff21, x1f, ln2_g, ln2_b, (float*)d_out, nullptr);
}

// Round 3
// 601.980 us; speedup vs baseline: 1.0089x; 1.0089x over previous
//
#include <hip/hip_runtime.h>
#include <hip/hip_bf16.h>

// GPT-2 transformer block, MI355X bf16-MFMA. Round 10 (= R9 + fencing fixes):
//  - gemm256: 256x256 tile, BK=32, 8 waves (512 thr), 4-deep LDS ring
//    (128 KiB), counted-vmcnt pipeline (stage t+3 while computing t;
//    steady-state s_waitcnt vmcnt(8), never vmcnt(0) in steady loop),
//    ONE fused asm {s_waitcnt; s_barrier} per K-tile, s_setprio(1) around
//    the 32-MFMA cluster, both-sides LDS XOR swizzle (slot ^= (row>>1)&3;
//    pre-swizzled global source for global_load_lds + swizzled ds_read_b128)
//    -> every 16-lane b128 pass hits all 8 bank-groups exactly 2x (free).
//  - R10 fix: waitcnt and s_barrier fused into a single asm volatile with
//    memory clobber, plus sched_barrier(0) fences after each sync point, so
//    hipcc cannot hoist ds_reads or sink global_load_lds across the counted
//    waits (rule-18 class hazard).
//  - split-K=2 only to fill the grid (proj, ff2: 256 blocks = 1 round);
//    partials fused into ln_kernel (3rd addend).
//  - attention: paired q-tiles (uniform work), unchanged.

typedef __attribute__((ext_vector_type(8))) short bf16x8;  // MFMA A/B frag
typedef __attribute__((ext_vector_type(4))) float f32x4;   // MFMA C/D frag

__device__ __forceinline__ unsigned short f2b(float f) {  // RNE
  unsigned int u = __float_as_uint(f);
  u += 0x7fffu + ((u >> 16) & 1u);
  return (unsigned short)(u >> 16);
}
__device__ __forceinline__ unsigned int pk2b(float a, float b) {  // packed bf16x2
  __hip_bfloat162 h = __float22bfloat162_rn(make_float2(a, b));
  return *(unsigned int*)&h;
}
__device__ __forceinline__ void gload_lds16(const unsigned short* g, unsigned short* l) {
  __builtin_amdgcn_global_load_lds((const __attribute__((address_space(1))) void*)g,
                                   (__attribute__((address_space(3))) void*)l, 16, 0, 0);
}

// ---------------- fp32 -> bf16 elementwise ----------------
__global__ __launch_bounds__(256) void cvt_bf16(const float* __restrict__ in,
                                                unsigned short* __restrict__ out, long n) {
  long i = ((long)blockIdx.x * 256 + threadIdx.x) * 4;
  if (i >= n) return;
  float4 v = *(const float4*)(in + i);
  *(ushort4*)(out + i) = make_ushort4(f2b(v.x), f2b(v.y), f2b(v.z), f2b(v.w));
}

// ---------------- transpose fp32 [R,C] -> bf16 [C,R] ----------------
__global__ __launch_bounds__(256) void transpose_bf16(const float* __restrict__ in,
                                                      unsigned short* __restrict__ out,
                                                      int R, int C) {
  __shared__ float tile[32][33];
  int c0 = blockIdx.x * 32, r0 = blockIdx.y * 32;
  for (int i = threadIdx.y; i < 32; i += 8)
    tile[i][threadIdx.x] = in[(long)(r0 + i) * C + c0 + threadIdx.x];
  __syncthreads();
  for (int i = threadIdx.y; i < 32; i += 8)
    out[(long)(c0 + i) * R + r0 + threadIdx.x] = f2b(tile[threadIdx.x][i]);
}

// ---------------- 256^2 deep-pipelined bf16 MFMA GEMM ----------------
// A [M][Kstride] bf16, Bt [N][Kstride] bf16. K = chunk length, blockIdx.y =
// K-chunk (0 -> Cout +bias, 1 -> Cout2 raw partial). M fixed 8192.
// Requires K%32==0, K>=128, N%256==0, gridDim.x%8==0.
// EPI: 0=f32 out, 2=bf16+relu,
//      3=qkv split: gn<2048 -> qk[m][2048] (q cols scaled 0.125*log2e),
//                   gn>=2048 -> vt[b,h,s,t] packed ushort4 scatter.
template <int EPI>
__global__ __launch_bounds__(512, 2) void gemm256(const unsigned short* __restrict__ A,
                                                  const unsigned short* __restrict__ Bt,
                                                  const float* __restrict__ bias,
                                                  void* __restrict__ Cout,
                                                  void* __restrict__ Cout2,
                                                  int N, int K, int Kstride) {
  __shared__ __align__(16) unsigned short As[4][256 * 32];  // 64 KiB ring
  __shared__ __align__(16) unsigned short Bs[4][256 * 32];  // 64 KiB ring

  int tid = threadIdx.x;
  int wv = tid >> 6, lane = tid & 63, quad = lane >> 4, l16 = lane & 15;
  int wm = wv >> 2, wn = wv & 3;  // 2x4 wave grid; wave owns 128x64 of C

  // XCD-aware bijective swizzle (gridDim.x % 8 == 0), bm-fastest
  int nwg = gridDim.x, id = blockIdx.x;
  int sid = (id & 7) * (nwg >> 3) + (id >> 3);
  int bm256 = (sid & 31) * 256, bn256 = (sid >> 5) * 256;
  int chunk = blockIdx.y;
  long kbase = (long)chunk * K;

  // staging: tile = 256 rows x 32 cols; thread handles 16B chunks tid and
  // tid+512. LDS chunk (row, slot) holds global chunk d = slot ^ ((row>>1)&3).
  int row1 = tid >> 2, row2 = row1 + 128;
  long dsl = ((tid & 3) ^ ((tid >> 3) & 3)) * 8;  // same swz term for row2 (+128)
  const unsigned short* Ap1 = A + (long)(bm256 + row1) * Kstride + kbase + dsl;
  const unsigned short* Ap2 = A + (long)(bm256 + row2) * Kstride + kbase + dsl;
  const unsigned short* Bp1 = Bt + (long)(bn256 + row1) * Kstride + kbase + dsl;
  const unsigned short* Bp2 = Bt + (long)(bn256 + row2) * Kstride + kbase + dsl;
  int ldsoff1 = wv * 512, ldsoff2 = wv * 512 + 4096;

  auto stage = [&](int t) {
    int buf = t & 3;
    long ko = (long)t * 32;
    gload_lds16(Ap1 + ko, &As[buf][ldsoff1]);
    gload_lds16(Ap2 + ko, &As[buf][ldsoff2]);
    gload_lds16(Bp1 + ko, &Bs[buf][ldsoff1]);
    gload_lds16(Bp2 + ko, &Bs[buf][ldsoff2]);
  };

  f32x4 acc[8][4] = {};
  // read-side swizzled 16B slot: (quad ^ ((row>>1)&3))*8, row%16 == l16
  int sl8 = (quad ^ ((l16 >> 1) & 3)) * 8;
  int arow = wm * 128 + l16;  // + i*16
  int brow = wn * 64 + l16;   // + j*16

  int NT = K >> 5;
  // prologue: 3 tiles in flight; wait for tile 0 (8 newest may remain)
  stage(0); stage(1); stage(2);
  asm volatile("s_waitcnt vmcnt(8)\n\ts_barrier" ::: "memory");
  __builtin_amdgcn_sched_barrier(0);

  for (int t = 0; t < NT; ++t) {
    if (t + 3 < NT) stage(t + 3);
    __builtin_amdgcn_sched_barrier(0);
    const unsigned short* Ab = &As[t & 3][0];
    const unsigned short* Bb = &Bs[t & 3][0];
    bf16x8 af[8], bfr[4];
#pragma unroll
    for (int i = 0; i < 8; ++i)
      af[i] = *(const bf16x8*)(Ab + (arow + i * 16) * 32 + sl8);
#pragma unroll
    for (int j = 0; j < 4; ++j)
      bfr[j] = *(const bf16x8*)(Bb + (brow + j * 16) * 32 + sl8);
    __builtin_amdgcn_s_setprio(1);
#pragma unroll
    for (int i = 0; i < 8; ++i)
#pragma unroll
      for (int j = 0; j < 4; ++j)
        acc[i][j] = __builtin_amdgcn_mfma_f32_16x16x32_bf16(af[i], bfr[j], acc[i][j], 0, 0, 0);
    __builtin_amdgcn_s_setprio(0);
    __builtin_amdgcn_sched_barrier(0);
    if (t + 1 < NT) {
      // counted wait fused with barrier: tile t+1 must have landed; the
      // newest in-flight tiles may stay outstanding across the barrier.
      if (t + 3 < NT)       asm volatile("s_waitcnt vmcnt(8)\n\ts_barrier" ::: "memory");
      else if (t + 3 == NT) asm volatile("s_waitcnt vmcnt(4)\n\ts_barrier" ::: "memory");
      else                  asm volatile("s_waitcnt vmcnt(0)\n\ts_barrier" ::: "memory");
      __builtin_amdgcn_sched_barrier(0);
    }
  }

  void* Cbase = chunk ? Cout2 : Cout;
#pragma unroll
  for (int i = 0; i < 8; ++i) {
#pragma unroll
    for (int j = 0; j < 4; ++j) {
      int gn = bn256 + wn * 64 + j * 16 + l16;
      float bv = chunk ? 0.f : bias[gn];
      if (EPI == 3 && gn >= 2048) {
        int h = (gn >> 6) & 15, s = gn & 63;
        int gm0 = bm256 + wm * 128 + i * 16 + quad * 4;
        int b = gm0 >> 11, tt0 = gm0 & 2047;
        unsigned short* vt = (unsigned short*)Cout + 16777216L;
        ushort4 us;
        us.x = f2b(acc[i][j][0] + bv);
        us.y = f2b(acc[i][j][1] + bv);
        us.z = f2b(acc[i][j][2] + bv);
        us.w = f2b(acc[i][j][3] + bv);
        *(ushort4*)(vt + (((long)(b * 16 + h)) * 64 + s) * 2048 + tt0) = us;
      } else {
#pragma unroll
        for (int r = 0; r < 4; ++r) {
          int gm = bm256 + wm * 128 + i * 16 + quad * 4 + r;
          float v = acc[i][j][r] + bv;
          if (EPI == 2) v = fmaxf(v, 0.f);
          if (EPI == 0) {
            ((float*)Cbase)[(long)gm * N + gn] = v;
          } else if (EPI == 2) {
            ((unsigned short*)Cbase)[(long)gm * N + gn] = f2b(v);
          } else {  // EPI==3, q/k rows
            float sc = (gn < 1024) ? 0.18033688011112042f : 1.0f;  // 0.125*log2(e)
            ((unsigned short*)Cbase)[(long)gm * 2048 + gn] = f2b(v * sc);
          }
        }
      }
    }
  }
}

// ---------------- MFMA flash attention (paired q-tiles, uniform work) --------
__global__ __launch_bounds__(256) void attn_mfma(const unsigned short* __restrict__ qkv,
                                                 unsigned short* __restrict__ outp) {
  const int LD = 72;  // 144 B row stride; b64/b128 accesses land 2-way (free)
  __shared__ __align__(16) unsigned short Ks[64 * LD];
  __shared__ __align__(16) unsigned short Vts[64 * LD];
  __shared__ __align__(16) unsigned short Ps[4][16 * LD];  // wave-private P rows
  int qa = blockIdx.x, qb = 31 - qa;  // paired q-tiles
  int h = blockIdx.y, b = blockIdx.z;
  int t = threadIdx.x;
  int w = t >> 6, lane = t & 63, quad = lane >> 4, l16 = lane & 15;
  const unsigned short* qg = qkv + (long)(b * 2048) * 2048 + h * 64;
  const unsigned short* kg = qg + 1024;
  const unsigned short* vg = qkv + 16777216L + (((long)(b * 16 + h)) * 64) * 2048;
  unsigned short* Pw = &Ps[w][0];

  bf16x8 qfa[2], qfb[2];
#pragma unroll
  for (int ks = 0; ks < 2; ++ks) {
    qfa[ks] = *(const bf16x8*)(qg + (long)(qa * 64 + w * 16 + l16) * 2048 + ks * 32 + quad * 8);
    qfb[ks] = *(const bf16x8*)(qg + (long)(qb * 64 + w * 16 + l16) * 2048 + ks * 32 + quad * 8);
  }

  int sr = t >> 2, sc = (t & 3) * 16;
  const unsigned short* kp = kg + (long)sr * 2048 + sc;
  const unsigned short* vp = vg + (long)sr * 2048 + sc;
  int4 kv0 = *(const int4*)kp, kv1 = *(const int4*)(kp + 8);
  int4 vv0 = *(const int4*)vp, vv1 = *(const int4*)(vp + 8);
  kp += (long)64 * 2048;
  vp += 64;

  f32x4 oa[4] = {}, ob[4] = {};
  f32x4 la = {}, lb = {};
  const short ONE = 0x3F80;
  bf16x8 ones = {ONE, ONE, ONE, ONE, ONE, ONE, ONE, ONE};

  auto process = [&](const bf16x8* qf, int qt, int kt, f32x4* oacc, f32x4& lacc) {
    bool diag = (kt == qt);
#pragma unroll
    for (int rg = 0; rg < 4; ++rg) {
      bf16x8 kf0 = *(const bf16x8*)(Ks + (rg * 16 + l16) * LD + quad * 8);
      bf16x8 kf1 = *(const bf16x8*)(Ks + (rg * 16 + l16) * LD + 32 + quad * 8);
      f32x4 st = {};
      st = __builtin_amdgcn_mfma_f32_16x16x32_bf16(kf0, qf[0], st, 0, 0, 0);
      st = __builtin_amdgcn_mfma_f32_16x16x32_bf16(kf1, qf[1], st, 0, 0, 0);
      if (diag) {
        int kq = rg * 16 + quad * 4;
        int qq = w * 16 + l16;
#pragma unroll
        for (int r = 0; r < 4; ++r)
          if (kq + r > qq) st[r] = -1e30f;
      }
      unsigned int lo = pk2b(exp2f(st[0]), exp2f(st[1]));
      unsigned int hi = pk2b(exp2f(st[2]), exp2f(st[3]));
      *(uint2*)(Pw + l16 * LD + rg * 16 + quad * 4) = make_uint2(lo, hi);
    }
#pragma unroll
    for (int kc = 0; kc < 2; ++kc) {
      bf16x8 ap = *(const bf16x8*)(Pw + l16 * LD + kc * 32 + quad * 8);
      lacc = __builtin_amdgcn_mfma_f32_16x16x32_bf16(ap, ones, lacc, 0, 0, 0);
#pragma unroll
      for (int sg = 0; sg < 4; ++sg) {
        bf16x8 vf = *(const bf16x8*)(Vts + (sg * 16 + l16) * LD + kc * 32 + quad * 8);
        oacc[sg] = __builtin_amdgcn_mfma_f32_16x16x32_bf16(ap, vf, oacc[sg], 0, 0, 0);
      }
    }
  };

  for (int kt = 0; kt <= qb; ++kt) {
    __syncthreads();
    *(int4*)(Ks + sr * LD + sc) = kv0;
    *(int4*)(Ks + sr * LD + sc + 8) = kv1;
    *(int4*)(Vts + sr * LD + sc) = vv0;
    *(int4*)(Vts + sr * LD + sc + 8) = vv1;
    __syncthreads();
    if (kt < qb) {
      kv0 = *(const int4*)kp; kv1 = *(const int4*)(kp + 8);
      vv0 = *(const int4*)vp; vv1 = *(const int4*)(vp + 8);
      kp += (long)64 * 2048;
      vp += 64;
    }
    process(qfb, qb, kt, ob, lb);
    if (kt <= qa) process(qfa, qa, kt, oa, la);
  }

  auto epi = [&](int qt, f32x4* oacc, f32x4& lacc) {
#pragma unroll
    for (int r = 0; r < 4; ++r) {
      float invl = 1.f / lacc[r];
      int row = qt * 64 + w * 16 + quad * 4 + r;
      unsigned short* op = outp + ((long)(b * 2048 + row)) * 1024 + h * 64;
#pragma unroll
      for (int sg = 0; sg < 4; ++sg) op[sg * 16 + l16] = f2b(oacc[sg][r] * invl);
    }
  };
  epi(qa, oa, la);
  epi(qb, ob, lb);
}

// ---------------- residual + LayerNorm (optional 3rd addend: split-K partial) --
__global__ __launch_bounds__(256) void ln_kernel(const float* __restrict__ a,
                                                 const float* __restrict__ a2,
                                                 const float* __restrict__ res,
                                                 const float* __restrict__ gam,
                                                 const float* __restrict__ bet,
                                                 float* __restrict__ outf,
                                                 unsigned short* __restrict__ outb) {
  int row = blockIdx.x, t = threadIdx.x;
  float4 av = *(const float4*)(a + (long)row * 1024 + t * 4);
  float4 rv = *(const float4*)(res + (long)row * 1024 + t * 4);
  float v0 = av.x + rv.x, v1 = av.y + rv.y, v2 = av.z + rv.z, v3 = av.w + rv.w;
  if (a2) {
    float4 a2v = *(const float4*)(a2 + (long)row * 1024 + t * 4);
    v0 += a2v.x; v1 += a2v.y; v2 += a2v.z; v3 += a2v.w;
  }
  float s = v0 + v1 + v2 + v3;
  float ss = v0 * v0 + v1 * v1 + v2 * v2 + v3 * v3;
#pragma unroll
  for (int off = 32; off >= 1; off >>= 1) {
    s += __shfl_down(s, off);
    ss += __shfl_down(ss, off);
  }
  __shared__ float sb[4], ssb[4];
  __shared__ float mean_s, inv_s;
  int w = t >> 6, lane = t & 63;
  if (lane == 0) { sb[w] = s; ssb[w] = ss; }
  __syncthreads();
  if (t == 0) {
    float S = sb[0] + sb[1] + sb[2] + sb[3];
    float SS = ssb[0] + ssb[1] + ssb[2] + ssb[3];
    float mean = S * (1.f / 1024.f);
    float var = SS * (1.f / 1024.f) - mean * mean;
    mean_s = mean;
    inv_s = rsqrtf(var + 1e-5f);
  }
  __syncthreads();
  float mean = mean_s, inv = inv_s;
  int c = t * 4;
  float4 gv = *(const float4*)(gam + c);
  float4 bv = *(const float4*)(bet + c);
  float y0 = (v0 - mean) * inv * gv.x + bv.x;
  float y1 = (v1 - mean) * inv * gv.y + bv.y;
  float y2 = (v2 - mean) * inv * gv.z + bv.z;
  float y3 = (v3 - mean) * inv * gv.w + bv.w;
  *(float4*)(outf + (long)row * 1024 + c) = make_float4(y0, y1, y2, y3);
  if (outb) {
    *(ushort4*)(outb + (long)row * 1024 + c) = make_ushort4(f2b(y0), f2b(y1), f2b(y2), f2b(y3));
  }
}

extern "C" void kernel_launch(void* const* d_in, const int* in_sizes, int n_in,
                              void* d_out, int out_size, void* d_ws, size_t ws_size,
                              hipStream_t stream) {
  const float* x      = (const float*)d_in[0];
  const float* w_attn = (const float*)d_in[1];
  const float* b_attn = (const float*)d_in[2];
  const float* w_proj = (const float*)d_in[3];
  const float* b_proj = (const float*)d_in[4];
  const float* ln1_g  = (const float*)d_in[5];
  const float* ln1_b  = (const float*)d_in[6];
  const float* w_ff1  = (const float*)d_in[7];
  const float* b_ff1  = (const float*)d_in[8];
  const float* w_ff2  = (const float*)d_in[9];
  const float* b_ff2  = (const float*)d_in[10];
  const float* ln2_g  = (const float*)d_in[11];
  const float* ln2_b  = (const float*)d_in[12];

  const long M = 8192, E = 1024;
  char* ws = (char*)d_ws;
  unsigned short* xb   = (unsigned short*)ws; ws += M * E * 2;           // 16 MiB
  unsigned short* wTa  = (unsigned short*)ws; ws += 3072L * 1024 * 2;    // 6
  unsigned short* wTp  = (unsigned short*)ws; ws += 1024L * 1024 * 2;    // 2
  unsigned short* wTf1 = (unsigned short*)ws; ws += 4096L * 1024 * 2;    // 8
  unsigned short* wTf2 = (unsigned short*)ws; ws += 4096L * 1024 * 2;    // 8
  unsigned short* qkvb = (unsigned short*)ws; ws += M * 3072 * 2;        // 48 (qk rows 32 MiB | vt 16 MiB)
  unsigned short* attb = (unsigned short*)ws; ws += M * E * 2;           // 16
  float* a1f = (float*)ws; ws += M * E * 4;                              // 32
  float* x1f = (float*)ws; ws += M * E * 4;                              // 32
  unsigned short* x1b = (unsigned short*)ws; ws += M * E * 2;            // 16  => 184 MiB
  unsigned short* hb = qkvb;   // overlays consumed qkv+attb space
  float* f2 = a1f;
  // split-K partial buffers (reuse dead workspace, both 32 MiB fp32):
  float* prj1 = (float*)qkvb;   // qk region dead after attn; ln1 consumes before ff1
  float* ff21 = (float*)d_ws;   // xb+wTa+wTp+(part of)wTf1 dead by ff2

  cvt_bf16<<<dim3((M * E) / 4 / 256), dim3(256), 0, stream>>>(x, xb, M * E);
  transpose_bf16<<<dim3(3072 / 32, 1024 / 32), dim3(32, 8), 0, stream>>>(w_attn, wTa, 1024, 3072);
  transpose_bf16<<<dim3(1024 / 32, 1024 / 32), dim3(32, 8), 0, stream>>>(w_proj, wTp, 1024, 1024);
  transpose_bf16<<<dim3(4096 / 32, 1024 / 32), dim3(32, 8), 0, stream>>>(w_ff1, wTf1, 1024, 4096);
  transpose_bf16<<<dim3(1024 / 32, 4096 / 32), dim3(32, 8), 0, stream>>>(w_ff2, wTf2, 4096, 1024);
  // qkv projection (384 blocks), attention-layout epilogue
  gemm256<3><<<dim3(384, 1), dim3(512), 0, stream>>>(xb, wTa, b_attn, qkvb, nullptr, 3072, 1024, 1024);
  // MFMA flash attention
  attn_mfma<<<dim3(16, 16, 4), dim3(256), 0, stream>>>(qkvb, attb);
  // attn output projection: split-K=2 -> 256 blocks = 1 full round
  gemm256<0><<<dim3(128, 2), dim3(512), 0, stream>>>(attb, wTp, b_proj, a1f, prj1, 1024, 512, 1024);
  ln_kernel<<<dim3(8192), dim3(256), 0, stream>>>(a1f, prj1, x, ln1_g, ln1_b, x1f, x1b);
  // ff1 (512 blocks = 2 rounds)
  gemm256<2><<<dim3(512, 1), dim3(512), 0, stream>>>(x1b, wTf1, b_ff1, hb, nullptr, 4096, 1024, 1024);
  // ff2: split-K=2 -> 256 blocks = 1 full round, K chunks of 2048
  gemm256<0><<<dim3(128, 2), dim3(512), 0, stream>>>(hb, wTf2, b_ff2, f2, ff21, 1024, 2048, 4096);
  ln_kernel<<<dim3(8192), dim3(256), 0, stream>>>(f2, ff21, x1f, ln2_g, ln2_b, (float*)d_out, nullptr);
}

// Round 4
// 567.094 us; speedup vs baseline: 1.0710x; 1.0615x over previous
//
#include <hip/hip_runtime.h>
#include <hip/hip_bf16.h>

// GPT-2 transformer block, MI355X bf16-MFMA. Round 11:
//  - gemm256 rebuilt as a TRUE per-phase pipeline (T3+T4+T5 on T2):
//    256x256 tile, BK=32, ring-4 LDS (128 KiB), 8 waves. Each K-tile = 2
//    phases; phase = {ds_read 8|4 x b128, stage 2 x global_load_lds (one
//    matrix of a tile 2-3 ahead), s_barrier+lgkmcnt(0)+sched_barrier,
//    setprio(1), 16 MFMA, setprio(0), barrier}. Counted vmcnt gate ONCE per
//    K-tile (end of odd phase): vmcnt(6) steady = 3 half-tile stages in
//    flight across barriers (tail 6->4->0); never a drain in steady state.
//    Ledger: stage(tau+2|3) targets slot (tau+2|3)&3, disjoint from slots
//    read this phase (distance 2 mod 4), >=2 barriers after last reader;
//    gate retires all stages older than the newest 3 before any wave
//    crosses the barrier that precedes tile tau+1's ds_reads.
//  - both-sides LDS XOR swizzle unchanged from R9/R10 (slot ^= (row>>1)&3,
//    pre-swizzled global source + swizzled ds_read_b128): each 16-lane b128
//    pass covers all 8 bank-groups exactly twice -> conflict-free.
//  - split-K=2 for proj/ff2 (grid fill), partials fused into ln_kernel.
//  - attention: paired q-tiles (uniform work), unchanged.

typedef __attribute__((ext_vector_type(8))) short bf16x8;  // MFMA A/B frag
typedef __attribute__((ext_vector_type(4))) float f32x4;   // MFMA C/D frag

__device__ __forceinline__ unsigned short f2b(float f) {  // RNE
  unsigned int u = __float_as_uint(f);
  u += 0x7fffu + ((u >> 16) & 1u);
  return (unsigned short)(u >> 16);
}
__device__ __forceinline__ unsigned int pk2b(float a, float b) {  // packed bf16x2
  __hip_bfloat162 h = __float22bfloat162_rn(make_float2(a, b));
  return *(unsigned int*)&h;
}
__device__ __forceinline__ void gload_lds16(const unsigned short* g, unsigned short* l) {
  __builtin_amdgcn_global_load_lds((const __attribute__((address_space(1))) void*)g,
                                   (__attribute__((address_space(3))) void*)l, 16, 0, 0);
}

// ---------------- fp32 -> bf16 elementwise ----------------
__global__ __launch_bounds__(256) void cvt_bf16(const float* __restrict__ in,
                                                unsigned short* __restrict__ out, long n) {
  long i = ((long)blockIdx.x * 256 + threadIdx.x) * 4;
  if (i >= n) return;
  float4 v = *(const float4*)(in + i);
  *(ushort4*)(out + i) = make_ushort4(f2b(v.x), f2b(v.y), f2b(v.z), f2b(v.w));
}

// ---------------- transpose fp32 [R,C] -> bf16 [C,R] ----------------
__global__ __launch_bounds__(256) void transpose_bf16(const float* __restrict__ in,
                                                      unsigned short* __restrict__ out,
                                                      int R, int C) {
  __shared__ float tile[32][33];
  int c0 = blockIdx.x * 32, r0 = blockIdx.y * 32;
  for (int i = threadIdx.y; i < 32; i += 8)
    tile[i][threadIdx.x] = in[(long)(r0 + i) * C + c0 + threadIdx.x];
  __syncthreads();
  for (int i = threadIdx.y; i < 32; i += 8)
    out[(long)(c0 + i) * R + r0 + threadIdx.x] = f2b(tile[threadIdx.x][i]);
}

// ---------------- 256^2 per-phase-pipelined bf16 MFMA GEMM ----------------
// A [M][Kstride] bf16, Bt [N][Kstride] bf16. K = chunk length, blockIdx.y =
// K-chunk (0 -> Cout +bias, 1 -> Cout2 raw partial). M fixed 8192.
// Requires K%32==0, K>=128, N%256==0, gridDim.x%8==0.
// EPI: 0=f32 out, 2=bf16+relu,
//      3=qkv split: gn<2048 -> qk[m][2048] (q cols scaled 0.125*log2e),
//                   gn>=2048 -> vt[b,h,s,t] packed ushort4 scatter.
template <int EPI>
__global__ __launch_bounds__(512, 2) void gemm256(const unsigned short* __restrict__ A,
                                                  const unsigned short* __restrict__ Bt,
                                                  const float* __restrict__ bias,
                                                  void* __restrict__ Cout,
                                                  void* __restrict__ Cout2,
                                                  int N, int K, int Kstride) {
  __shared__ __align__(16) unsigned short As[4][256 * 32];  // 64 KiB ring
  __shared__ __align__(16) unsigned short Bs[4][256 * 32];  // 64 KiB ring

  int tid = threadIdx.x;
  int wv = tid >> 6, lane = tid & 63, quad = lane >> 4, l16 = lane & 15;
  int wm = wv >> 2, wn = wv & 3;  // 2x4 wave grid; wave owns 128x64 of C

  // XCD-aware bijective swizzle (gridDim.x % 8 == 0), bm-fastest
  int nwg = gridDim.x, id = blockIdx.x;
  int sid = (id & 7) * (nwg >> 3) + (id >> 3);
  int bm256 = (sid & 31) * 256, bn256 = (sid >> 5) * 256;
  int chunk = blockIdx.y;
  long kbase = (long)chunk * K;

  // staging: tile = 256 rows x 32 cols; thread covers 16B chunks tid and
  // tid+512. LDS chunk (row, slot) holds global chunk d = slot ^ ((row>>1)&3).
  int row1 = tid >> 2, row2 = row1 + 128;
  long dsl = ((tid & 3) ^ ((tid >> 3) & 3)) * 8;  // inverse-swizzled source col
  const unsigned short* Ap1 = A + (long)(bm256 + row1) * Kstride + kbase + dsl;
  const unsigned short* Ap2 = A + (long)(bm256 + row2) * Kstride + kbase + dsl;
  const unsigned short* Bp1 = Bt + (long)(bn256 + row1) * Kstride + kbase + dsl;
  const unsigned short* Bp2 = Bt + (long)(bn256 + row2) * Kstride + kbase + dsl;
  int lo1 = wv * 512, lo2 = wv * 512 + 4096;

  f32x4 acc[8][4] = {};
  // read-side swizzled 16B slot: (quad ^ ((row>>1)&3))*8, row%16 == l16
  int sl8 = (quad ^ ((l16 >> 1) & 3)) * 8;
  int arow = wm * 128 + l16;  // + i*16
  int brow = wn * 64 + l16;   // + j*16

  int NT = K >> 5;  // always >= 16 here
  // prologue stages, issue order A0 B0 A1 B1 A2 (10 loads; newest 6 may fly)
  gload_lds16(Ap1, &As[0][lo1]); gload_lds16(Ap2, &As[0][lo2]);
  gload_lds16(Bp1, &Bs[0][lo1]); gload_lds16(Bp2, &Bs[0][lo2]);
  gload_lds16(Ap1 + 32, &As[1][lo1]); gload_lds16(Ap2 + 32, &As[1][lo2]);
  gload_lds16(Bp1 + 32, &Bs[1][lo1]); gload_lds16(Bp2 + 32, &Bs[1][lo2]);
  gload_lds16(Ap1 + 64, &As[2][lo1]); gload_lds16(Ap2 + 64, &As[2][lo2]);
  asm volatile("s_waitcnt vmcnt(6)\n\ts_barrier" ::: "memory");
  __builtin_amdgcn_sched_barrier(0);

  for (int tau = 0; tau < NT; ++tau) {
    const unsigned short* Ab = &As[tau & 3][0];
    const unsigned short* Bb = &Bs[tau & 3][0];
    bf16x8 af[4], bfr[4];
    // ---- even phase: read A i0-3 + B j0-3 (8 b128); stage B(tau+2); MFMA i0-3
#pragma unroll
    for (int i = 0; i < 4; ++i)
      af[i] = *(const bf16x8*)(Ab + (arow + i * 16) * 32 + sl8);
#pragma unroll
    for (int j = 0; j < 4; ++j)
      bfr[j] = *(const bf16x8*)(Bb + (brow + j * 16) * 32 + sl8);
    if (tau + 2 < NT) {
      long ko = (long)(tau + 2) * 32;
      int s = (tau + 2) & 3;
      gload_lds16(Bp1 + ko, &Bs[s][lo1]);
      gload_lds16(Bp2 + ko, &Bs[s][lo2]);
    }
    asm volatile("s_barrier\n\ts_waitcnt lgkmcnt(0)" ::: "memory");
    __builtin_amdgcn_sched_barrier(0);
    __builtin_amdgcn_s_setprio(1);
#pragma unroll
    for (int i = 0; i < 4; ++i)
#pragma unroll
      for (int j = 0; j < 4; ++j)
        acc[i][j] = __builtin_amdgcn_mfma_f32_16x16x32_bf16(af[i], bfr[j], acc[i][j], 0, 0, 0);
    __builtin_amdgcn_s_setprio(0);
    __builtin_amdgcn_s_barrier();
    __builtin_amdgcn_sched_barrier(0);
    // ---- odd phase: read A i4-7 (4 b128); stage A(tau+3); MFMA i4-7
    bf16x8 ag[4];
#pragma unroll
    for (int i = 0; i < 4; ++i)
      ag[i] = *(const bf16x8*)(Ab + (arow + (i + 4) * 16) * 32 + sl8);
    if (tau + 3 < NT) {
      long ko = (long)(tau + 3) * 32;
      int s = (tau + 3) & 3;
      gload_lds16(Ap1 + ko, &As[s][lo1]);
      gload_lds16(Ap2 + ko, &As[s][lo2]);
    }
    asm volatile("s_barrier\n\ts_waitcnt lgkmcnt(0)" ::: "memory");
    __builtin_amdgcn_sched_barrier(0);
    __builtin_amdgcn_s_setprio(1);
#pragma unroll
    for (int i = 0; i < 4; ++i)
#pragma unroll
      for (int j = 0; j < 4; ++j)
        acc[i + 4][j] = __builtin_amdgcn_mfma_f32_16x16x32_bf16(ag[i], bfr[j], acc[i + 4][j], 0, 0, 0);
    __builtin_amdgcn_s_setprio(0);
    // ---- once-per-tile counted gate + end barrier (tail: 6 -> 4 -> 0)
    if (tau + 3 < NT) {
      asm volatile("s_waitcnt vmcnt(6)\n\ts_barrier" ::: "memory");
    } else if (tau + 2 < NT) {
      asm volatile("s_waitcnt vmcnt(4)\n\ts_barrier" ::: "memory");
    } else if (tau + 1 < NT) {
      asm volatile("s_waitcnt vmcnt(0)\n\ts_barrier" ::: "memory");
    }
    __builtin_amdgcn_sched_barrier(0);
  }

  void* Cbase = chunk ? Cout2 : Cout;
#pragma unroll
  for (int i = 0; i < 8; ++i) {
#pragma unroll
    for (int j = 0; j < 4; ++j) {
      int gn = bn256 + wn * 64 + j * 16 + l16;
      float bv = chunk ? 0.f : bias[gn];
      if (EPI == 3 && gn >= 2048) {
        int h = (gn >> 6) & 15, s = gn & 63;
        int gm0 = bm256 + wm * 128 + i * 16 + quad * 4;
        int b = gm0 >> 11, tt0 = gm0 & 2047;
        unsigned short* vt = (unsigned short*)Cout + 16777216L;
        ushort4 us;
        us.x = f2b(acc[i][j][0] + bv);
        us.y = f2b(acc[i][j][1] + bv);
        us.z = f2b(acc[i][j][2] + bv);
        us.w = f2b(acc[i][j][3] + bv);
        *(ushort4*)(vt + (((long)(b * 16 + h)) * 64 + s) * 2048 + tt0) = us;
      } else {
#pragma unroll
        for (int r = 0; r < 4; ++r) {
          int gm = bm256 + wm * 128 + i * 16 + quad * 4 + r;
          float v = acc[i][j][r] + bv;
          if (EPI == 2) v = fmaxf(v, 0.f);
          if (EPI == 0) {
            ((float*)Cbase)[(long)gm * N + gn] = v;
          } else if (EPI == 2) {
            ((unsigned short*)Cbase)[(long)gm * N + gn] = f2b(v);
          } else {  // EPI==3, q/k rows
            float sc = (gn < 1024) ? 0.18033688011112042f : 1.0f;  // 0.125*log2(e)
            ((unsigned short*)Cbase)[(long)gm * 2048 + gn] = f2b(v * sc);
          }
        }
      }
    }
  }
}

// ---------------- MFMA flash attention (paired q-tiles, uniform work) --------
__global__ __launch_bounds__(256) void attn_mfma(const unsigned short* __restrict__ qkv,
                                                 unsigned short* __restrict__ outp) {
  const int LD = 72;  // 144 B row stride; b64/b128 accesses land 2-way (free)
  __shared__ __align__(16) unsigned short Ks[64 * LD];
  __shared__ __align__(16) unsigned short Vts[64 * LD];
  __shared__ __align__(16) unsigned short Ps[4][16 * LD];  // wave-private P rows
  int qa = blockIdx.x, qb = 31 - qa;  // paired q-tiles
  int h = blockIdx.y, b = blockIdx.z;
  int t = threadIdx.x;
  int w = t >> 6, lane = t & 63, quad = lane >> 4, l16 = lane & 15;
  const unsigned short* qg = qkv + (long)(b * 2048) * 2048 + h * 64;
  const unsigned short* kg = qg + 1024;
  const unsigned short* vg = qkv + 16777216L + (((long)(b * 16 + h)) * 64) * 2048;
  unsigned short* Pw = &Ps[w][0];

  bf16x8 qfa[2], qfb[2];
#pragma unroll
  for (int ks = 0; ks < 2; ++ks) {
    qfa[ks] = *(const bf16x8*)(qg + (long)(qa * 64 + w * 16 + l16) * 2048 + ks * 32 + quad * 8);
    qfb[ks] = *(const bf16x8*)(qg + (long)(qb * 64 + w * 16 + l16) * 2048 + ks * 32 + quad * 8);
  }

  int sr = t >> 2, sc = (t & 3) * 16;
  const unsigned short* kp = kg + (long)sr * 2048 + sc;
  const unsigned short* vp = vg + (long)sr * 2048 + sc;
  int4 kv0 = *(const int4*)kp, kv1 = *(const int4*)(kp + 8);
  int4 vv0 = *(const int4*)vp, vv1 = *(const int4*)(vp + 8);
  kp += (long)64 * 2048;
  vp += 64;

  f32x4 oa[4] = {}, ob[4] = {};
  f32x4 la = {}, lb = {};
  const short ONE = 0x3F80;
  bf16x8 ones = {ONE, ONE, ONE, ONE, ONE, ONE, ONE, ONE};

  auto process = [&](const bf16x8* qf, int qt, int kt, f32x4* oacc, f32x4& lacc) {
    bool diag = (kt == qt);
#pragma unroll
    for (int rg = 0; rg < 4; ++rg) {
      bf16x8 kf0 = *(const bf16x8*)(Ks + (rg * 16 + l16) * LD + quad * 8);
      bf16x8 kf1 = *(const bf16x8*)(Ks + (rg * 16 + l16) * LD + 32 + quad * 8);
      f32x4 st = {};
      st = __builtin_amdgcn_mfma_f32_16x16x32_bf16(kf0, qf[0], st, 0, 0, 0);
      st = __builtin_amdgcn_mfma_f32_16x16x32_bf16(kf1, qf[1], st, 0, 0, 0);
      if (diag) {
        int kq = rg * 16 + quad * 4;
        int qq = w * 16 + l16;
#pragma unroll
        for (int r = 0; r < 4; ++r)
          if (kq + r > qq) st[r] = -1e30f;
      }
      unsigned int lo = pk2b(exp2f(st[0]), exp2f(st[1]));
      unsigned int hi = pk2b(exp2f(st[2]), exp2f(st[3]));
      *(uint2*)(Pw + l16 * LD + rg * 16 + quad * 4) = make_uint2(lo, hi);
    }
#pragma unroll
    for (int kc = 0; kc < 2; ++kc) {
      bf16x8 ap = *(const bf16x8*)(Pw + l16 * LD + kc * 32 + quad * 8);
      lacc = __builtin_amdgcn_mfma_f32_16x16x32_bf16(ap, ones, lacc, 0, 0, 0);
#pragma unroll
      for (int sg = 0; sg < 4; ++sg) {
        bf16x8 vf = *(const bf16x8*)(Vts + (sg * 16 + l16) * LD + kc * 32 + quad * 8);
        oacc[sg] = __builtin_amdgcn_mfma_f32_16x16x32_bf16(ap, vf, oacc[sg], 0, 0, 0);
      }
    }
  };

  for (int kt = 0; kt <= qb; ++kt) {
    __syncthreads();
    *(int4*)(Ks + sr * LD + sc) = kv0;
    *(int4*)(Ks + sr * LD + sc + 8) = kv1;
    *(int4*)(Vts + sr * LD + sc) = vv0;
    *(int4*)(Vts + sr * LD + sc + 8) = vv1;
    __syncthreads();
    if (kt < qb) {
      kv0 = *(const int4*)kp; kv1 = *(const int4*)(kp + 8);
      vv0 = *(const int4*)vp; vv1 = *(const int4*)(vp + 8);
      kp += (long)64 * 2048;
      vp += 64;
    }
    process(qfb, qb, kt, ob, lb);
    if (kt <= qa) process(qfa, qa, kt, oa, la);
  }

  auto epi = [&](int qt, f32x4* oacc, f32x4& lacc) {
#pragma unroll
    for (int r = 0; r < 4; ++r) {
      float invl = 1.f / lacc[r];
      int row = qt * 64 + w * 16 + quad * 4 + r;
      unsigned short* op = outp + ((long)(b * 2048 + row)) * 1024 + h * 64;
#pragma unroll
      for (int sg = 0; sg < 4; ++sg) op[sg * 16 + l16] = f2b(oacc[sg][r] * invl);
    }
  };
  epi(qa, oa, la);
  epi(qb, ob, lb);
}

// ---------------- residual + LayerNorm (optional 3rd addend: split-K partial) --
__global__ __launch_bounds__(256) void ln_kernel(const float* __restrict__ a,
                                                 const float* __restrict__ a2,
                                                 const float* __restrict__ res,
                                                 const float* __restrict__ gam,
                                                 const float* __restrict__ bet,
                                                 float* __restrict__ outf,
                                                 unsigned short* __restrict__ outb) {
  int row = blockIdx.x, t = threadIdx.x;
  float4 av = *(const float4*)(a + (long)row * 1024 + t * 4);
  float4 rv = *(const float4*)(res + (long)row * 1024 + t * 4);
  float v0 = av.x + rv.x, v1 = av.y + rv.y, v2 = av.z + rv.z, v3 = av.w + rv.w;
  if (a2) {
    float4 a2v = *(const float4*)(a2 + (long)row * 1024 + t * 4);
    v0 += a2v.x; v1 += a2v.y; v2 += a2v.z; v3 += a2v.w;
  }
  float s = v0 + v1 + v2 + v3;
  float ss = v0 * v0 + v1 * v1 + v2 * v2 + v3 * v3;
#pragma unroll
  for (int off = 32; off >= 1; off >>= 1) {
    s += __shfl_down(s, off);
    ss += __shfl_down(ss, off);
  }
  __shared__ float sb[4], ssb[4];
  __shared__ float mean_s, inv_s;
  int w = t >> 6, lane = t & 63;
  if (lane == 0) { sb[w] = s; ssb[w] = ss; }
  __syncthreads();
  if (t == 0) {
    float S = sb[0] + sb[1] + sb[2] + sb[3];
    float SS = ssb[0] + ssb[1] + ssb[2] + ssb[3];
    float mean = S * (1.f / 1024.f);
    float var = SS * (1.f / 1024.f) - mean * mean;
    mean_s = mean;
    inv_s = rsqrtf(var + 1e-5f);
  }
  __syncthreads();
  float mean = mean_s, inv = inv_s;
  int c = t * 4;
  float4 gv = *(const float4*)(gam + c);
  float4 bv = *(const float4*)(bet + c);
  float y0 = (v0 - mean) * inv * gv.x + bv.x;
  float y1 = (v1 - mean) * inv * gv.y + bv.y;
  float y2 = (v2 - mean) * inv * gv.z + bv.z;
  float y3 = (v3 - mean) * inv * gv.w + bv.w;
  *(float4*)(outf + (long)row * 1024 + c) = make_float4(y0, y1, y2, y3);
  if (outb) {
    *(ushort4*)(outb + (long)row * 1024 + c) = make_ushort4(f2b(y0), f2b(y1), f2b(y2), f2b(y3));
  }
}

extern "C" void kernel_launch(void* const* d_in, const int* in_sizes, int n_in,
                              void* d_out, int out_size, void* d_ws, size_t ws_size,
                              hipStream_t stream) {
  const float* x      = (const float*)d_in[0];
  const float* w_attn = (const float*)d_in[1];
  const float* b_attn = (const float*)d_in[2];
  const float* w_proj = (const float*)d_in[3];
  const float* b_proj = (const float*)d_in[4];
  const float* ln1_g  = (const float*)d_in[5];
  const float* ln1_b  = (const float*)d_in[6];
  const float* w_ff1  = (const float*)d_in[7];
  const float* b_ff1  = (const float*)d_in[8];
  const float* w_ff2  = (const float*)d_in[9];
  const float* b_ff2  = (const float*)d_in[10];
  const float* ln2_g  = (const float*)d_in[11];
  const float* ln2_b  = (const float*)d_in[12];

  const long M = 8192, E = 1024;
  char* ws = (char*)d_ws;
  unsigned short* xb   = (unsigned short*)ws; ws += M * E * 2;           // 16 MiB
  unsigned short* wTa  = (unsigned short*)ws; ws += 3072L * 1024 * 2;    // 6
  unsigned short* wTp  = (unsigned short*)ws; ws += 1024L * 1024 * 2;    // 2
  unsigned short* wTf1 = (unsigned short*)ws; ws += 4096L * 1024 * 2;    // 8
  unsigned short* wTf2 = (unsigned short*)ws; ws += 4096L * 1024 * 2;    // 8
  unsigned short* qkvb = (unsigned short*)ws; ws += M * 3072 * 2;        // 48 (qk rows 32 MiB | vt 16 MiB)
  unsigned short* attb = (unsigned short*)ws; ws += M * E * 2;           // 16
  float* a1f = (float*)ws; ws += M * E * 4;                              // 32
  float* x1f = (float*)ws; ws += M * E * 4;                              // 32
  unsigned short* x1b = (unsigned short*)ws; ws += M * E * 2;            // 16  => 184 MiB
  unsigned short* hb = qkvb;   // overlays consumed qkv+attb space
  float* f2 = a1f;
  // split-K partial buffers (reuse dead workspace, both 32 MiB fp32):
  float* prj1 = (float*)qkvb;   // qk region dead after attn; ln1 consumes before ff1
  float* ff21 = (float*)d_ws;   // xb+wTa+wTp+(part of)wTf1 dead by ff2

  cvt_bf16<<<dim3((M * E) / 4 / 256), dim3(256), 0, stream>>>(x, xb, M * E);
  transpose_bf16<<<dim3(3072 / 32, 1024 / 32), dim3(32, 8), 0, stream>>>(w_attn, wTa, 1024, 3072);
  transpose_bf16<<<dim3(1024 / 32, 1024 / 32), dim3(32, 8), 0, stream>>>(w_proj, wTp, 1024, 1024);
  transpose_bf16<<<dim3(4096 / 32, 1024 / 32), dim3(32, 8), 0, stream>>>(w_ff1, wTf1, 1024, 4096);
  transpose_bf16<<<dim3(1024 / 32, 4096 / 32), dim3(32, 8), 0, stream>>>(w_ff2, wTf2, 4096, 1024);
  // qkv projection (384 blocks), attention-layout epilogue
  gemm256<3><<<dim3(384, 1), dim3(512), 0, stream>>>(xb, wTa, b_attn, qkvb, nullptr, 3072, 1024, 1024);
  // MFMA flash attention
  attn_mfma<<<dim3(16, 16, 4), dim3(256), 0, stream>>>(qkvb, attb);
  // attn output projection: split-K=2 -> 256 blocks = 1 full round
  gemm256<0><<<dim3(128, 2), dim3(512), 0, stream>>>(attb, wTp, b_proj, a1f, prj1, 1024, 512, 1024);
  ln_kernel<<<dim3(8192), dim3(256), 0, stream>>>(a1f, prj1, x, ln1_g, ln1_b, x1f, x1b);
  // ff1 (512 blocks = 2 rounds)
  gemm256<2><<<dim3(512, 1), dim3(512), 0, stream>>>(x1b, wTf1, b_ff1, hb, nullptr, 4096, 1024, 1024);
  // ff2: split-K=2 -> 256 blocks = 1 full round, K chunks of 2048
  gemm256<0><<<dim3(128, 2), dim3(512), 0, stream>>>(hb, wTf2, b_ff2, f2, ff21, 1024, 2048, 4096);
  ln_kernel<<<dim3(8192), dim3(256), 0, stream>>>(f2, ff21, x1f, ln2_g, ln2_b, (float*)d_out, nullptr);
}